// Round 6
// baseline (1359.085 us; speedup 1.0000x reference)
//
#include <hip/hip_runtime.h>

// NodeGCN: GCNConv + 2x GINConv (edge-attr MLPs) + BN + concat + 2-layer head.
// Round 6: (1) all node GEMMs -> bf16 MFMA (templated, fused epilogues: BN,
// relu, gin-pre, bf16 feature table); feats kept bf16-only [N][288].
// (2) edge kernel: bias-in-C-init, XOR-swizzled unpadded LDS (30720B ->
// 5 blocks/CU), launch_bounds(256,5). (3) CSR build fused 10->6 kernels.

#define HH 96
#define EDGEF 16
#define CAT (3 * HH)

typedef __attribute__((ext_vector_type(8))) short bf16x8;
typedef __attribute__((ext_vector_type(4))) float f32x4;
typedef __attribute__((ext_vector_type(4))) unsigned short ubf16x4;

__device__ __forceinline__ unsigned short f2bf(float f) {
    unsigned u = __float_as_uint(f);
    u += 0x7fffu + ((u >> 16) & 1u);      // round-to-nearest-even
    return (unsigned short)(u >> 16);
}
__device__ __forceinline__ float bf2f(unsigned short s) {
    return __uint_as_float(((unsigned)s) << 16);
}

// ---------------- unified MFMA node GEMM -----------------------------------------
// C[M,F] = epi(A_eff[M,K] @ W[K,F] + bias)
// AMODE: 0 = f32 A; 1 = bf16 A; 2 = gin-pre (A_eff = (1+eps)*bf16 h + f32 agg)
// EPI:   0 = f32 C; 1 = relu->bf16 C; 2 = relu->BN->bf16 C; 3 = f32 C + bf16 copy
// Frag mapping (verified R2): A row=lr,k=8lg+j; B col=lr,k=8lg+j; D row=4lg+reg,col=lr.
template <int K, int F, int AMODE, int EPI>
__global__ __launch_bounds__(256) void node_gemm(
    const void* __restrict__ Aptr, int lda,
    const float* __restrict__ agg,
    const float* __restrict__ eps_arr, int li,
    const float* __restrict__ W, const float* __restrict__ bias,
    void* __restrict__ Cptr, int ldc,
    unsigned short* __restrict__ bf_copy,
    const float* __restrict__ gamma, const float* __restrict__ beta,
    const float* __restrict__ mean, const float* __restrict__ var,
    int M)
{
    constexpr int SW = ((K * 2) % 128 == 0) ? 7 : 3;   // XOR span fits row stride
    constexpr int NFT = F / 16;
    __shared__ __align__(16) short s_wt[F * K];        // W^T bf16, XOR-swizzled

    const int tid = threadIdx.x;
    const int lane = tid & 63;
    const int w = tid >> 6;
    const int lr = lane & 15;
    const int lg = lane >> 4;

    for (int idx = tid; idx < F * K; idx += 256) {
        int f = idx / K, k = idx - f * K;
        s_wt[idx ^ ((f & SW) << 3)] = (short)f2bf(W[k * F + f]);
    }
    __syncthreads();

    const int R0 = blockIdx.x * 64 + 16 * w;
    const int Ra = min(R0 + lr, M - 1);

    float e1 = 0.f;
    if (AMODE == 2) e1 = 1.f + eps_arr[li];

    f32x4 acc[NFT];
#pragma unroll
    for (int ft = 0; ft < NFT; ++ft) {
        float b = bias[16 * ft + lr];
        acc[ft][0] = b; acc[ft][1] = b; acc[ft][2] = b; acc[ft][3] = b;
    }

#pragma unroll
    for (int kt = 0; kt < K / 32; ++kt) {
        bf16x8 ae;
        if (AMODE == 0) {
            const float* ap = (const float*)Aptr + (size_t)Ra * lda + 32 * kt + 8 * lg;
            f32x4 a0 = *(const f32x4*)ap;
            f32x4 a1 = *(const f32x4*)(ap + 4);
#pragma unroll
            for (int j = 0; j < 4; ++j) {
                ae[j] = (short)f2bf(a0[j]); ae[4 + j] = (short)f2bf(a1[j]);
            }
        } else if (AMODE == 1) {
            ae = *(const bf16x8*)((const unsigned short*)Aptr + (size_t)Ra * lda + 32 * kt + 8 * lg);
        } else {
            const unsigned short* hp = (const unsigned short*)Aptr + (size_t)Ra * lda + 32 * kt + 8 * lg;
            bf16x8 h8 = *(const bf16x8*)hp;
            const float* gp = agg + (size_t)Ra * HH + 32 * kt + 8 * lg;
            f32x4 g0 = *(const f32x4*)gp;
            f32x4 g1 = *(const f32x4*)(gp + 4);
#pragma unroll
            for (int j = 0; j < 4; ++j) {
                ae[j]     = (short)f2bf(fmaf(e1, bf2f((unsigned short)h8[j]), g0[j]));
                ae[4 + j] = (short)f2bf(fmaf(e1, bf2f((unsigned short)h8[4 + j]), g1[j]));
            }
        }
#pragma unroll
        for (int ft = 0; ft < NFT; ++ft) {
            bf16x8 bw = *(const bf16x8*)&s_wt[((lr + 16 * ft) * K + 32 * kt + 8 * lg) ^ ((lr & SW) << 3)];
            acc[ft] = __builtin_amdgcn_mfma_f32_16x16x32_bf16(ae, bw, acc[ft], 0, 0, 0);
        }
    }

    float scale[NFT], shiftv[NFT];
    if (EPI == 2) {
#pragma unroll
        for (int ft = 0; ft < NFT; ++ft) {
            int col = 16 * ft + lr;
            float s = gamma[col] * rsqrtf(var[col] + 1e-5f);
            scale[ft] = s;
            shiftv[ft] = beta[col] - mean[col] * s;
        }
    }
#pragma unroll
    for (int reg = 0; reg < 4; ++reg) {
        int r = R0 + 4 * lg + reg;
        if (r < M) {
#pragma unroll
            for (int ft = 0; ft < NFT; ++ft) {
                int col = 16 * ft + lr;
                float v = acc[ft][reg];
                if (EPI == 0) {
                    ((float*)Cptr)[(size_t)r * ldc + col] = v;
                } else if (EPI == 1) {
                    ((unsigned short*)Cptr)[(size_t)r * ldc + col] = f2bf(fmaxf(v, 0.f));
                } else if (EPI == 2) {
                    float z = fmaxf(v, 0.f) * scale[ft] + shiftv[ft];
                    ((unsigned short*)Cptr)[(size_t)r * ldc + col] = f2bf(z);
                } else {
                    ((float*)Cptr)[(size_t)r * ldc + col] = v;
                    bf_copy[(size_t)r * F + col] = f2bf(v);
                }
            }
        }
    }
}

// ---------------- CSR build (fused) ----------------------------------------------
__global__ void init_kernel(float* __restrict__ deg, int* __restrict__ cnt, int N)
{
    int i = blockIdx.x * blockDim.x + threadIdx.x;
    if (i < N) { deg[i] = 1.f; cnt[i] = 0; }
}

__global__ void count_kernel(const int* __restrict__ row, const int* __restrict__ col,
                             float* __restrict__ deg, int* __restrict__ cnt, int E)
{
    int e = blockIdx.x * blockDim.x + threadIdx.x;
    if (e < E) {
        atomicAdd(&deg[row[e]], 1.f);
        atomicAdd(&cnt[col[e]], 1);
    }
}

__global__ void scan1_kernel(const int* __restrict__ cnt, int* __restrict__ start,
                             int* __restrict__ bsum, int N)
{
    __shared__ int s[256];
    int tid = threadIdx.x;
    int i = blockIdx.x * 256 + tid;
    int v = (i < N) ? cnt[i] : 0;
    s[tid] = v;
    __syncthreads();
#pragma unroll
    for (int off = 1; off < 256; off <<= 1) {
        int t = (tid >= off) ? s[tid - off] : 0;
        __syncthreads();
        s[tid] += t;
        __syncthreads();
    }
    if (i < N) start[i] = s[tid] - v;
    if (tid == 255) bsum[blockIdx.x] = s[255];
}

__global__ void scan2_kernel(int* __restrict__ bsum, int nb)
{
    __shared__ int s[256];
    int tid = threadIdx.x;
    int v = (tid < nb) ? bsum[tid] : 0;
    s[tid] = v;
    __syncthreads();
#pragma unroll
    for (int off = 1; off < 256; off <<= 1) {
        int t = (tid >= off) ? s[tid - off] : 0;
        __syncthreads();
        s[tid] += t;
        __syncthreads();
    }
    if (tid < nb) bsum[tid] = s[tid] - v;
}

__global__ void scan3_kernel(int* __restrict__ start, const int* __restrict__ bsum,
                             int* __restrict__ cursor,
                             const float* __restrict__ deg, float* __restrict__ dinv,
                             int N, int E)
{
    int i = blockIdx.x * blockDim.x + threadIdx.x;
    if (i < N) {
        int f = start[i] + bsum[i >> 8];
        start[i] = f;
        cursor[i] = f;
        dinv[i] = rsqrtf(deg[i]);
    } else if (i == N) {
        start[N] = E;
    }
}

// scatter + edge_attr permute+cvt fused (edge_order array eliminated)
__global__ void scatter_ea_kernel(const int* __restrict__ row, const int* __restrict__ col,
                                  int* __restrict__ cursor,
                                  const float* __restrict__ ea,
                                  int* __restrict__ row_sorted,
                                  unsigned short* __restrict__ eas, int E)
{
    int e = blockIdx.x * blockDim.x + threadIdx.x;
    if (e >= E) return;
    int c = col[e];
    int p = atomicAdd(&cursor[c], 1);
    row_sorted[p] = row[e];
    const float* src = ea + (size_t)e * EDGEF;
    f32x4 v0 = *(const f32x4*)(src);
    f32x4 v1 = *(const f32x4*)(src + 4);
    f32x4 v2 = *(const f32x4*)(src + 8);
    f32x4 v3 = *(const f32x4*)(src + 12);
    bf16x8 o0, o1;
#pragma unroll
    for (int j = 0; j < 4; ++j) {
        o0[j] = (short)f2bf(v0[j]); o0[4 + j] = (short)f2bf(v1[j]);
        o1[j] = (short)f2bf(v2[j]); o1[4 + j] = (short)f2bf(v3[j]);
    }
    *(bf16x8*)(eas + (size_t)p * EDGEF) = o0;
    *(bf16x8*)(eas + (size_t)p * EDGEF + 8) = o1;
}

// ---------------- node-centric MFMA edge kernel ----------------------------------
// One wave per destination node. Unpadded LDS with XOR swizzle (byte^=((row&3)<<4));
// biases folded into MFMA C-init; masked accumulate via one fmaf.
template <bool GCN>
__global__ __launch_bounds__(256, 5) void edge_kernel(
    const unsigned short* __restrict__ ea_sorted,
    const int* __restrict__ row_sorted,
    const int* __restrict__ seg_start,
    const float* __restrict__ bw1, const float* __restrict__ bb1,
    const float* __restrict__ bw2, const float* __restrict__ bb2,
    const unsigned short* __restrict__ hbf, int hstride,
    const float* __restrict__ dinv,
    float* __restrict__ agg,
    int N)
{
    __shared__ __align__(16) short s_bw2T[96 * 96];   // bw2^T bf16, swizzled 18432B
    __shared__ __align__(16) short s_t[4 * 16 * 96];  // per-wave t / h park   12288B

    const int tid = threadIdx.x;
    const int lane = tid & 63;
    const int w = tid >> 6;
    const int lr = lane & 15;
    const int lg = lane >> 4;
    const int wbase = w * 16 * 96;
    const int rsw = (lr & 3) << 3;                    // row-lr swizzle (shorts)

    for (int idx = tid; idx < HH * HH; idx += 256) {
        int k = idx / HH, f = idx - k * HH;
        s_bw2T[(f * HH + k) ^ ((f & 3) << 3)] = (short)f2bf(bw2[idx]);
    }

    // persistent per-lane constants
    bf16x8 bwf[6];                                    // bw1 B-frags (lg<2 real)
#pragma unroll
    for (int ft = 0; ft < 6; ++ft)
#pragma unroll
        for (int j = 0; j < 8; ++j) bwf[ft][j] = 0;
    if (lg < 2) {
#pragma unroll
        for (int ft = 0; ft < 6; ++ft)
#pragma unroll
            for (int j = 0; j < 8; ++j)
                bwf[ft][j] = (short)f2bf(bw1[(8 * lg + j) * HH + lr + 16 * ft]);
    }
    float bsv[6];                                     // bb1 per D-col (GEMM1)
    f32x4 bb2r[6];                                    // bb2 per D-row-quad (GEMM2)
#pragma unroll
    for (int ft = 0; ft < 6; ++ft) {
        bsv[ft] = bb1[lr + 16 * ft];
        bb2r[ft] = *(const f32x4*)&bb2[16 * ft + 4 * lg];
    }
    __syncthreads();

    const int nwaves = gridDim.x * 4;

    for (int c = blockIdx.x * 4 + w; c < N; c += nwaves) {
        const int s0 = seg_start[c];
        const int s1 = seg_start[c + 1];
        const float dinv_c = GCN ? dinv[c] : 1.f;

        f32x4 acc[6];
#pragma unroll
        for (int ft = 0; ft < 6; ++ft) { acc[ft][0]=0.f; acc[ft][1]=0.f; acc[ft][2]=0.f; acc[ft][3]=0.f; }

        for (int b = s0; b < s1; b += 16) {
            const int epos = b + lr;
            const bool vld = (epos < s1);
            const int epc = vld ? epos : s0;
            const int r = row_sorted[epc];

            // prefetch full h row (lane (lr,lg): 48B chunk lg of row lr)
            const unsigned short* hrow = hbf + (size_t)r * hstride + 24 * lg;
            bf16x8 h0 = *(const bf16x8*)(hrow);
            bf16x8 h1 = *(const bf16x8*)(hrow + 8);
            bf16x8 h2 = *(const bf16x8*)(hrow + 16);

            const float msk = vld ? (GCN ? dinv[r] * dinv_c : 1.f) : 0.f;

            // A-frag: sequential 16B bf16 load (k<16 real, rest zero)
            bf16x8 ae;
#pragma unroll
            for (int j = 0; j < 8; ++j) ae[j] = 0;
            if (lg < 2)
                ae = *(const bf16x8*)(ea_sorted + (size_t)epc * EDGEF + 8 * lg);

            // GEMM1 (bias in C-init) + relu -> s_t [edge][feat]
#pragma unroll
            for (int ft = 0; ft < 6; ++ft) {
                f32x4 ci; ci[0]=bsv[ft]; ci[1]=bsv[ft]; ci[2]=bsv[ft]; ci[3]=bsv[ft];
                f32x4 tacc = __builtin_amdgcn_mfma_f32_16x16x32_bf16(ae, bwf[ft], ci, 0, 0, 0);
#pragma unroll
                for (int reg = 0; reg < 4; ++reg) {
                    float v = fmaxf(tacc[reg], 0.f);
                    s_t[(wbase + (4 * lg + reg) * 96 + lr + 16 * ft) ^ (reg << 3)] = (short)f2bf(v);
                }
            }
            __builtin_amdgcn_wave_barrier();    // t writes before bt reads

            // GEMM2 B-frags: t^T, col=edge=lr
            bf16x8 bt[3];
#pragma unroll
            for (int kt = 0; kt < 3; ++kt)
                bt[kt] = *(const bf16x8*)&s_t[(wbase + lr * 96 + 8 * lg + 32 * kt) ^ rsw];
            __builtin_amdgcn_wave_barrier();    // bt reads before h overwrites

            // park h rows in the freed slice
            *(bf16x8*)&s_t[(wbase + lr * 96 + 24 * lg) ^ rsw]      = h0;
            *(bf16x8*)&s_t[(wbase + lr * 96 + 24 * lg + 8) ^ rsw]  = h1;
            *(bf16x8*)&s_t[(wbase + lr * 96 + 24 * lg + 16) ^ rsw] = h2;
            __builtin_amdgcn_wave_barrier();    // h writes before hv reads

            // GEMM2 (swapped, bias in C-init) + epilogue
#pragma unroll
            for (int ft = 0; ft < 6; ++ft) {
                f32x4 ee = bb2r[ft];
#pragma unroll
                for (int kt = 0; kt < 3; ++kt) {
                    bf16x8 aw = *(const bf16x8*)&s_bw2T[((lr + 16 * ft) * 96 + 8 * lg + 32 * kt) ^ rsw];
                    ee = __builtin_amdgcn_mfma_f32_16x16x32_bf16(aw, bt[kt], ee, 0, 0, 0);
                }
                const int fb = 16 * ft + 4 * lg;
                ubf16x4 hv = *(const ubf16x4*)&s_t[(wbase + lr * 96 + fb) ^ rsw];
#pragma unroll
                for (int reg = 0; reg < 4; ++reg) {
                    float m = fmaxf(bf2f(hv[reg]) + ee[reg], 0.f);
                    acc[ft][reg] = fmaf(m, msk, acc[ft][reg]);
                }
            }
        }

        // reduce over the 16-edge lane dimension
#pragma unroll
        for (int ft = 0; ft < 6; ++ft) {
#pragma unroll
            for (int reg = 0; reg < 4; ++reg) {
                float v = acc[ft][reg];
                v += __shfl_xor(v, 1);
                v += __shfl_xor(v, 2);
                v += __shfl_xor(v, 4);
                v += __shfl_xor(v, 8);
                acc[ft][reg] = v;
            }
        }
        if (lr == 0) {
#pragma unroll
            for (int ft = 0; ft < 6; ++ft)
                *(f32x4*)&agg[(size_t)c * HH + 16 * ft + 4 * lg] = acc[ft];
        }
    }
}

// ---------------- GCN epilogue (f32 agg+self -> BN -> bf16 feats) ----------------
__global__ void gcn_epilogue_kernel(
    const float* __restrict__ agg, const float* __restrict__ hbuf,
    const float* __restrict__ root, const float* __restrict__ deg,
    const float* __restrict__ gamma, const float* __restrict__ beta,
    const float* __restrict__ mean, const float* __restrict__ var,
    unsigned short* __restrict__ featsbf, int N)
{
    int idx = blockIdx.x * blockDim.x + threadIdx.x;   // quad index
    if (idx >= N * (HH / 4)) return;
    int n = idx / (HH / 4), q = idx - n * (HH / 4);
    int f0 = 4 * q;
    f32x4 a  = *(const f32x4*)&agg[(size_t)n * HH + f0];
    f32x4 h  = *(const f32x4*)&hbuf[(size_t)n * HH + f0];
    f32x4 rt = *(const f32x4*)&root[f0];
    f32x4 gm = *(const f32x4*)&gamma[f0];
    f32x4 bt = *(const f32x4*)&beta[f0];
    f32x4 mn = *(const f32x4*)&mean[f0];
    f32x4 vr = *(const f32x4*)&var[f0];
    float di = 1.f / deg[n];
    ubf16x4 o;
#pragma unroll
    for (int j = 0; j < 4; ++j) {
        float self = fmaxf(h[j] + rt[j], 0.f) * di;
        float v = fmaxf(a[j] + self, 0.f);
        v = (v - mn[j]) * rsqrtf(vr[j] + 1e-5f) * gm[j] + bt[j];
        o[j] = f2bf(v);
    }
    *(ubf16x4*)&featsbf[(size_t)n * CAT + f0] = o;
}

// ---------------- launch ----------------------------------------------------------
extern "C" void kernel_launch(void* const* d_in, const int* in_sizes, int n_in,
                              void* d_out, int out_size, void* d_ws, size_t ws_size,
                              hipStream_t stream)
{
    const float* x         = (const float*)d_in[0];
    const int*   eidx      = (const int*)d_in[1];
    const float* edge_attr = (const float*)d_in[2];
    const float* gcn_lin_w = (const float*)d_in[3];
    const float* gcn_lin_b = (const float*)d_in[4];
    const float* gcn_root  = (const float*)d_in[5];
    const float* gcn_bw1   = (const float*)d_in[6];
    const float* gcn_bb1   = (const float*)d_in[7];
    const float* gcn_bw2   = (const float*)d_in[8];
    const float* gcn_bb2   = (const float*)d_in[9];
    const float* gin_bw1   = (const float*)d_in[10];
    const float* gin_bb1   = (const float*)d_in[11];
    const float* gin_bw2   = (const float*)d_in[12];
    const float* gin_bb2   = (const float*)d_in[13];
    const float* gin_mw1   = (const float*)d_in[14];
    const float* gin_mb1   = (const float*)d_in[15];
    const float* gin_mw2   = (const float*)d_in[16];
    const float* gin_mb2   = (const float*)d_in[17];
    const float* gin_eps   = (const float*)d_in[18];
    const float* bn_gamma  = (const float*)d_in[19];
    const float* bn_beta   = (const float*)d_in[20];
    const float* bn_mean   = (const float*)d_in[21];
    const float* bn_var    = (const float*)d_in[22];
    const float* fc1_w     = (const float*)d_in[23];
    const float* fc1_b     = (const float*)d_in[24];
    const float* fc2_w     = (const float*)d_in[25];
    const float* fc2_b     = (const float*)d_in[26];
    float* out = (float*)d_out;

    const int N = in_sizes[0] / 128;   // 50000
    const int E = in_sizes[1] / 2;     // 800000
    const int* row = eidx;
    const int* col = eidx + E;

    // ws layout (bytes)
    char* ws = (char*)d_ws;
    float* deg        = (float*)(ws);                          // N f32
    float* dinv       = (float*)(ws + (size_t)256 * 1024);     // N f32
    int*   seg_start  = (int*)(ws + (size_t)512 * 1024);       // N+1
    int*   cursor     = (int*)(ws + (size_t)768 * 1024);       // N (also hist cnt)
    int*   bsum       = (int*)(ws + (size_t)1024 * 1024);      // 256
    int*   row_sorted = (int*)(ws + (size_t)1088 * 1024);      // E (3.2MB)
    unsigned short* ea_sorted = (unsigned short*)(ws + (size_t)8 * 1024 * 1024);    // E*16 bf16
    unsigned short* hb        = (unsigned short*)(ws + (size_t)34 * 1024 * 1024);   // N*96 bf16
    float* hbuf   = (float*)(ws + (size_t)44 * 1024 * 1024);   // N*96 f32
    float* agg    = (float*)(ws + (size_t)64 * 1024 * 1024);   // N*96 f32
    unsigned short* featsbf = (unsigned short*)(ws + (size_t)84 * 1024 * 1024);     // N*288 bf16
    unsigned short* z1bf    = (unsigned short*)(ws + (size_t)113 * 1024 * 1024);    // N*96 bf16
    unsigned short* r1bf    = (unsigned short*)(ws + (size_t)123 * 1024 * 1024);    // N*96 bf16

    const int ew_blocks = 1280;                     // 5 blocks/CU x 256 CU
    const int q_grid = (N * (HH / 4) + 255) / 256;
    const int gemm_grid = (N + 63) / 64;
    const int e_grid = (E + 255) / 256;
    const int n_grid = (N + 255) / 256;
    const int nchunks = (N + 255) / 256;

    // ---- degrees + CSR build ----
    init_kernel<<<n_grid, 256, 0, stream>>>(deg, cursor, N);
    count_kernel<<<e_grid, 256, 0, stream>>>(row, col, deg, cursor, E);
    scan1_kernel<<<nchunks, 256, 0, stream>>>(cursor, seg_start, bsum, N);
    scan2_kernel<<<1, 256, 0, stream>>>(bsum, nchunks);
    scan3_kernel<<<(N + 256) / 256, 256, 0, stream>>>(seg_start, bsum, cursor, deg, dinv, N, E);
    scatter_ea_kernel<<<e_grid, 256, 0, stream>>>(row, col, cursor, edge_attr,
                                                  row_sorted, ea_sorted, E);

    // ---- layer 0: GCN ----
    node_gemm<128, 96, 0, 3><<<gemm_grid, 256, 0, stream>>>(
        x, 128, nullptr, nullptr, 0, gcn_lin_w, gcn_lin_b,
        hbuf, HH, hb, nullptr, nullptr, nullptr, nullptr, N);
    edge_kernel<true><<<ew_blocks, 256, 0, stream>>>(
        ea_sorted, row_sorted, seg_start,
        gcn_bw1, gcn_bb1, gcn_bw2, gcn_bb2, hb, HH, dinv, agg, N);
    gcn_epilogue_kernel<<<q_grid, 256, 0, stream>>>(
        agg, hbuf, gcn_root, deg, bn_gamma, bn_beta, bn_mean, bn_var, featsbf, N);

    // ---- layers 1..2: GIN ----
    for (int i = 0; i < 2; ++i) {
        edge_kernel<false><<<ew_blocks, 256, 0, stream>>>(
            ea_sorted, row_sorted, seg_start,
            gin_bw1 + (size_t)i * EDGEF * HH, gin_bb1 + i * HH,
            gin_bw2 + (size_t)i * HH * HH, gin_bb2 + i * HH,
            featsbf + i * HH, CAT, dinv, agg, N);
        // z1 = relu((1+eps)*h + agg) @ mw1 + mb1  -> bf16
        node_gemm<96, 96, 2, 1><<<gemm_grid, 256, 0, stream>>>(
            featsbf + i * HH, CAT, agg, gin_eps, i,
            gin_mw1 + (size_t)i * HH * HH, gin_mb1 + i * HH,
            z1bf, HH, nullptr, nullptr, nullptr, nullptr, nullptr, N);
        // feats[i+1] = BN(relu(z1 @ mw2 + mb2))  -> bf16 strided
        node_gemm<96, 96, 1, 2><<<gemm_grid, 256, 0, stream>>>(
            z1bf, HH, nullptr, nullptr, 0,
            gin_mw2 + (size_t)i * HH * HH, gin_mb2 + i * HH,
            featsbf + (i + 1) * HH, CAT, nullptr,
            bn_gamma + (i + 1) * HH, bn_beta + (i + 1) * HH,
            bn_mean + (i + 1) * HH, bn_var + (i + 1) * HH, N);
    }

    // ---- head ----
    node_gemm<288, 96, 1, 1><<<gemm_grid, 256, 0, stream>>>(
        featsbf, CAT, nullptr, nullptr, 0, fc1_w, fc1_b,
        r1bf, HH, nullptr, nullptr, nullptr, nullptr, nullptr, N);
    node_gemm<96, 64, 1, 0><<<gemm_grid, 256, 0, stream>>>(
        r1bf, HH, nullptr, nullptr, 0, fc2_w, fc2_b,
        out, 64, nullptr, nullptr, nullptr, nullptr, nullptr, N);
}

// Round 7
// 696.888 us; speedup vs baseline: 1.9502x; 1.9502x over previous
//
#include <hip/hip_runtime.h>

// NodeGCN: GCNConv + 2x GINConv (edge-attr MLPs) + BN + concat + 2-layer head.
// Round 7: R6 regressed (spills from launch_bounds(256,5)+persistent reg arrays
// -> 924MB scratch FETCH; bad swizzle -> 16M conflicts). Revert edge kernel to
// the proven R5 config (134us: (256,4), padded LDS, weights/biases from LDS).
// Keep R6's MFMA node pipeline but write dense bf16 h-tables (hb [N][96]) from
// every epilogue so the edge kernel never reads strided feats.

#define HH 96
#define EDGEF 16
#define CAT (3 * HH)

typedef __attribute__((ext_vector_type(8))) short bf16x8;
typedef __attribute__((ext_vector_type(4))) float f32x4;
typedef __attribute__((ext_vector_type(4))) unsigned short ubf16x4;

__device__ __forceinline__ unsigned short f2bf(float f) {
    unsigned u = __float_as_uint(f);
    u += 0x7fffu + ((u >> 16) & 1u);      // round-to-nearest-even
    return (unsigned short)(u >> 16);
}
__device__ __forceinline__ float bf2f(unsigned short s) {
    return __uint_as_float(((unsigned)s) << 16);
}

// ---------------- unified MFMA node GEMM -----------------------------------------
// C[M,F] = epi(A_eff[M,K] @ W[K,F] + bias)
// AMODE: 0 = f32 A; 1 = bf16 A; 2 = gin-pre (A_eff = (1+eps)*bf16 h + f32 agg)
// EPI:   0 = f32 C; 1 = relu->bf16 C; 2 = relu->BN->bf16 C + dense bf16 copy;
//        3 = f32 C + dense bf16 copy
// Frag mapping (verified R2): A row=lr,k=8lg+j; B col=lr,k=8lg+j; D row=4lg+reg,col=lr.
template <int K, int F, int AMODE, int EPI>
__global__ __launch_bounds__(256) void node_gemm(
    const void* __restrict__ Aptr, int lda,
    const float* __restrict__ agg,
    const float* __restrict__ eps_arr, int li,
    const float* __restrict__ W, const float* __restrict__ bias,
    void* __restrict__ Cptr, int ldc,
    unsigned short* __restrict__ bf_copy,
    const float* __restrict__ gamma, const float* __restrict__ beta,
    const float* __restrict__ mean, const float* __restrict__ var,
    int M)
{
    constexpr int SW = ((K * 2) % 128 == 0) ? 7 : 3;   // XOR span fits row stride
    constexpr int NFT = F / 16;
    __shared__ __align__(16) short s_wt[F * K];        // W^T bf16, XOR-swizzled

    const int tid = threadIdx.x;
    const int lane = tid & 63;
    const int w = tid >> 6;
    const int lr = lane & 15;
    const int lg = lane >> 4;

    for (int idx = tid; idx < F * K; idx += 256) {
        int f = idx / K, k = idx - f * K;
        s_wt[idx ^ ((f & SW) << 3)] = (short)f2bf(W[k * F + f]);
    }
    __syncthreads();

    const int R0 = blockIdx.x * 64 + 16 * w;
    const int Ra = min(R0 + lr, M - 1);

    float e1 = 0.f;
    if (AMODE == 2) e1 = 1.f + eps_arr[li];

    f32x4 acc[NFT];
#pragma unroll
    for (int ft = 0; ft < NFT; ++ft) {
        float b = bias[16 * ft + lr];
        acc[ft][0] = b; acc[ft][1] = b; acc[ft][2] = b; acc[ft][3] = b;
    }

#pragma unroll
    for (int kt = 0; kt < K / 32; ++kt) {
        bf16x8 ae;
        if (AMODE == 0) {
            const float* ap = (const float*)Aptr + (size_t)Ra * lda + 32 * kt + 8 * lg;
            f32x4 a0 = *(const f32x4*)ap;
            f32x4 a1 = *(const f32x4*)(ap + 4);
#pragma unroll
            for (int j = 0; j < 4; ++j) {
                ae[j] = (short)f2bf(a0[j]); ae[4 + j] = (short)f2bf(a1[j]);
            }
        } else if (AMODE == 1) {
            ae = *(const bf16x8*)((const unsigned short*)Aptr + (size_t)Ra * lda + 32 * kt + 8 * lg);
        } else {
            const unsigned short* hp = (const unsigned short*)Aptr + (size_t)Ra * lda + 32 * kt + 8 * lg;
            bf16x8 h8 = *(const bf16x8*)hp;
            const float* gp = agg + (size_t)Ra * HH + 32 * kt + 8 * lg;
            f32x4 g0 = *(const f32x4*)gp;
            f32x4 g1 = *(const f32x4*)(gp + 4);
#pragma unroll
            for (int j = 0; j < 4; ++j) {
                ae[j]     = (short)f2bf(fmaf(e1, bf2f((unsigned short)h8[j]), g0[j]));
                ae[4 + j] = (short)f2bf(fmaf(e1, bf2f((unsigned short)h8[4 + j]), g1[j]));
            }
        }
#pragma unroll
        for (int ft = 0; ft < NFT; ++ft) {
            bf16x8 bw = *(const bf16x8*)&s_wt[((lr + 16 * ft) * K + 32 * kt + 8 * lg) ^ ((lr & SW) << 3)];
            acc[ft] = __builtin_amdgcn_mfma_f32_16x16x32_bf16(ae, bw, acc[ft], 0, 0, 0);
        }
    }

    float scale[NFT], shiftv[NFT];
    if (EPI == 2) {
#pragma unroll
        for (int ft = 0; ft < NFT; ++ft) {
            int col = 16 * ft + lr;
            float s = gamma[col] * rsqrtf(var[col] + 1e-5f);
            scale[ft] = s;
            shiftv[ft] = beta[col] - mean[col] * s;
        }
    }
#pragma unroll
    for (int reg = 0; reg < 4; ++reg) {
        int r = R0 + 4 * lg + reg;
        if (r < M) {
#pragma unroll
            for (int ft = 0; ft < NFT; ++ft) {
                int col = 16 * ft + lr;
                float v = acc[ft][reg];
                if (EPI == 0) {
                    ((float*)Cptr)[(size_t)r * ldc + col] = v;
                } else if (EPI == 1) {
                    ((unsigned short*)Cptr)[(size_t)r * ldc + col] = f2bf(fmaxf(v, 0.f));
                } else if (EPI == 2) {
                    float z = fmaxf(v, 0.f) * scale[ft] + shiftv[ft];
                    unsigned short zb = f2bf(z);
                    ((unsigned short*)Cptr)[(size_t)r * ldc + col] = zb;
                    bf_copy[(size_t)r * F + col] = zb;
                } else {
                    ((float*)Cptr)[(size_t)r * ldc + col] = v;
                    bf_copy[(size_t)r * F + col] = f2bf(v);
                }
            }
        }
    }
}

// ---------------- CSR build (fused) ----------------------------------------------
__global__ void init_kernel(float* __restrict__ deg, int* __restrict__ cnt, int N)
{
    int i = blockIdx.x * blockDim.x + threadIdx.x;
    if (i < N) { deg[i] = 1.f; cnt[i] = 0; }
}

__global__ void count_kernel(const int* __restrict__ row, const int* __restrict__ col,
                             float* __restrict__ deg, int* __restrict__ cnt, int E)
{
    int e = blockIdx.x * blockDim.x + threadIdx.x;
    if (e < E) {
        atomicAdd(&deg[row[e]], 1.f);
        atomicAdd(&cnt[col[e]], 1);
    }
}

__global__ void scan1_kernel(const int* __restrict__ cnt, int* __restrict__ start,
                             int* __restrict__ bsum, int N)
{
    __shared__ int s[256];
    int tid = threadIdx.x;
    int i = blockIdx.x * 256 + tid;
    int v = (i < N) ? cnt[i] : 0;
    s[tid] = v;
    __syncthreads();
#pragma unroll
    for (int off = 1; off < 256; off <<= 1) {
        int t = (tid >= off) ? s[tid - off] : 0;
        __syncthreads();
        s[tid] += t;
        __syncthreads();
    }
    if (i < N) start[i] = s[tid] - v;
    if (tid == 255) bsum[blockIdx.x] = s[255];
}

__global__ void scan2_kernel(int* __restrict__ bsum, int nb)
{
    __shared__ int s[256];
    int tid = threadIdx.x;
    int v = (tid < nb) ? bsum[tid] : 0;
    s[tid] = v;
    __syncthreads();
#pragma unroll
    for (int off = 1; off < 256; off <<= 1) {
        int t = (tid >= off) ? s[tid - off] : 0;
        __syncthreads();
        s[tid] += t;
        __syncthreads();
    }
    if (tid < nb) bsum[tid] = s[tid] - v;
}

__global__ void scan3_kernel(int* __restrict__ start, const int* __restrict__ bsum,
                             int* __restrict__ cursor,
                             const float* __restrict__ deg, float* __restrict__ dinv,
                             int N, int E)
{
    int i = blockIdx.x * blockDim.x + threadIdx.x;
    if (i < N) {
        int f = start[i] + bsum[i >> 8];
        start[i] = f;
        cursor[i] = f;
        dinv[i] = rsqrtf(deg[i]);
    } else if (i == N) {
        start[N] = E;
    }
}

// scatter + edge_attr permute+cvt fused
__global__ void scatter_ea_kernel(const int* __restrict__ row, const int* __restrict__ col,
                                  int* __restrict__ cursor,
                                  const float* __restrict__ ea,
                                  int* __restrict__ row_sorted,
                                  unsigned short* __restrict__ eas, int E)
{
    int e = blockIdx.x * blockDim.x + threadIdx.x;
    if (e >= E) return;
    int c = col[e];
    int p = atomicAdd(&cursor[c], 1);
    row_sorted[p] = row[e];
    const float* src = ea + (size_t)e * EDGEF;
    f32x4 v0 = *(const f32x4*)(src);
    f32x4 v1 = *(const f32x4*)(src + 4);
    f32x4 v2 = *(const f32x4*)(src + 8);
    f32x4 v3 = *(const f32x4*)(src + 12);
    bf16x8 o0, o1;
#pragma unroll
    for (int j = 0; j < 4; ++j) {
        o0[j] = (short)f2bf(v0[j]); o0[4 + j] = (short)f2bf(v1[j]);
        o1[j] = (short)f2bf(v2[j]); o1[4 + j] = (short)f2bf(v3[j]);
    }
    *(bf16x8*)(eas + (size_t)p * EDGEF) = o0;
    *(bf16x8*)(eas + (size_t)p * EDGEF + 8) = o1;
}

// ---------------- node-centric MFMA edge kernel (R5-proven config) ---------------
// One wave per destination node. Per 16-edge batch: h rows prefetched whole
// (3x16B/lane at batch start, latency hidden under GEMM1), parked in the freed
// s_t wave slice; epilogue reads hv from LDS. Weights/biases from padded LDS,
// no persistent register arrays (VGPR ~52, no spill at (256,4)).
template <bool GCN>
__global__ __launch_bounds__(256, 4) void edge_kernel(
    const unsigned short* __restrict__ ea_sorted,
    const int* __restrict__ row_sorted,
    const int* __restrict__ seg_start,
    const float* __restrict__ bw1, const float* __restrict__ bb1,
    const float* __restrict__ bw2, const float* __restrict__ bb2,
    const unsigned short* __restrict__ hbf,
    const float* __restrict__ dinv,
    float* __restrict__ agg,
    int N)
{
    __shared__ __align__(16) short s_bw2T[96][104];   // bw2^T bf16 [f][k] 19968B
    __shared__ __align__(16) short s_bw1T[96][16];    // bw1^T bf16 [f][k]  3072B
    __shared__ __align__(16) short s_t[4][16][104];   // per-wave t / h park 13312B
    __shared__ float s_bias[192];                     // bb1 | bb2            768B

    const int tid = threadIdx.x;
    const int lane = tid & 63;
    const int w = tid >> 6;
    const int lr = lane & 15;
    const int lg = lane >> 4;

    for (int idx = tid; idx < HH * HH; idx += 256) {
        int k = idx / HH, f = idx - k * HH;
        s_bw2T[f][k] = (short)f2bf(bw2[idx]);
    }
    for (int idx = tid; idx < EDGEF * HH; idx += 256) {
        int k = idx / HH, f = idx - k * HH;
        s_bw1T[f][k] = (short)f2bf(bw1[idx]);
    }
    if (tid < HH) { s_bias[tid] = bb1[tid]; s_bias[HH + tid] = bb2[tid]; }
    __syncthreads();

    const f32x4 zf = {0.f, 0.f, 0.f, 0.f};
    const int nwaves = gridDim.x * 4;

    for (int c = blockIdx.x * 4 + w; c < N; c += nwaves) {
        const int s0 = seg_start[c];
        const int s1 = seg_start[c + 1];
        float dinv_c = GCN ? dinv[c] : 1.f;

        f32x4 acc[6];
#pragma unroll
        for (int ft = 0; ft < 6; ++ft) acc[ft] = zf;

        for (int b = s0; b < s1; b += 16) {
            const int epos = b + lr;
            const bool vld = (epos < s1);
            const int epc = vld ? epos : s0;
            const int r = row_sorted[epc];

            // prefetch full h row (lane (lr,lg) covers 48B chunk lg of row lr)
            const unsigned short* hrow = hbf + (size_t)r * HH + 24 * lg;
            bf16x8 h0 = *(const bf16x8*)(hrow);
            bf16x8 h1 = *(const bf16x8*)(hrow + 8);
            bf16x8 h2 = *(const bf16x8*)(hrow + 16);

            float nrm = GCN ? dinv[r] * dinv_c : 1.f;

            // A-frag: sequential 16B bf16 load (k<16 real, rest zero)
            bf16x8 ae;
#pragma unroll
            for (int j = 0; j < 8; ++j) ae[j] = 0;
            if (lg < 2)
                ae = *(const bf16x8*)(ea_sorted + (size_t)epc * EDGEF + 8 * lg);

            // GEMM1 + bias + relu -> s_t (t layout [edge][feat])
#pragma unroll
            for (int ft = 0; ft < 6; ++ft) {
                bf16x8 b1;
#pragma unroll
                for (int j = 0; j < 8; ++j) b1[j] = 0;
                if (lg < 2)
                    b1 = *(const bf16x8*)&s_bw1T[lr + 16 * ft][8 * lg];
                f32x4 tacc = __builtin_amdgcn_mfma_f32_16x16x32_bf16(ae, b1, zf, 0, 0, 0);
                float bsv = s_bias[lr + 16 * ft];
#pragma unroll
                for (int reg = 0; reg < 4; ++reg) {
                    float v = fmaxf(tacc[reg] + bsv, 0.f);
                    s_t[w][4 * lg + reg][lr + 16 * ft] = (short)f2bf(v);
                }
            }
            __builtin_amdgcn_wave_barrier();    // t writes before bt reads

            // GEMM2 B-frags: t^T, col=edge=lr
            bf16x8 bt[3];
#pragma unroll
            for (int kt = 0; kt < 3; ++kt)
                bt[kt] = *(const bf16x8*)&s_t[w][lr][8 * lg + 32 * kt];
            __builtin_amdgcn_wave_barrier();    // bt reads before h overwrites

            // park h rows in the freed slice (lane (lr,lg) -> row lr, chunk lg)
            *(bf16x8*)&s_t[w][lr][24 * lg]      = h0;
            *(bf16x8*)&s_t[w][lr][24 * lg + 8]  = h1;
            *(bf16x8*)&s_t[w][lr][24 * lg + 16] = h2;
            __builtin_amdgcn_wave_barrier();    // h writes before hv reads

            // GEMM2 (swapped) + epilogue
#pragma unroll
            for (int ft = 0; ft < 6; ++ft) {
                f32x4 ee = zf;
#pragma unroll
                for (int kt = 0; kt < 3; ++kt) {
                    bf16x8 aw = *(const bf16x8*)&s_bw2T[lr + 16 * ft][8 * lg + 32 * kt];
                    ee = __builtin_amdgcn_mfma_f32_16x16x32_bf16(aw, bt[kt], ee, 0, 0, 0);
                }
                const int fb = 16 * ft + 4 * lg;
                f32x4 bb = *(const f32x4*)&s_bias[HH + fb];
                ubf16x4 hv = *(const ubf16x4*)&s_t[w][lr][fb];
#pragma unroll
                for (int reg = 0; reg < 4; ++reg) {
                    float m = fmaxf(bf2f(hv[reg]) + ee[reg] + bb[reg], 0.f) * nrm;
                    acc[ft][reg] += vld ? m : 0.f;
                }
            }
        }

        // reduce over the 16-edge lane dimension
#pragma unroll
        for (int ft = 0; ft < 6; ++ft) {
#pragma unroll
            for (int reg = 0; reg < 4; ++reg) {
                float v = acc[ft][reg];
                v += __shfl_xor(v, 1);
                v += __shfl_xor(v, 2);
                v += __shfl_xor(v, 4);
                v += __shfl_xor(v, 8);
                acc[ft][reg] = v;
            }
        }
        if (lr == 0) {
#pragma unroll
            for (int ft = 0; ft < 6; ++ft)
                *(f32x4*)&agg[(size_t)c * HH + 16 * ft + 4 * lg] = acc[ft];
        }
    }
}

// ---------------- GCN epilogue (f32 agg+self -> BN -> bf16 feats + dense hb) -----
__global__ void gcn_epilogue_kernel(
    const float* __restrict__ agg, const float* __restrict__ hbuf,
    const float* __restrict__ root, const float* __restrict__ deg,
    const float* __restrict__ gamma, const float* __restrict__ beta,
    const float* __restrict__ mean, const float* __restrict__ var,
    unsigned short* __restrict__ featsbf, unsigned short* __restrict__ hb, int N)
{
    int idx = blockIdx.x * blockDim.x + threadIdx.x;   // quad index
    if (idx >= N * (HH / 4)) return;
    int n = idx / (HH / 4), q = idx - n * (HH / 4);
    int f0 = 4 * q;
    f32x4 a  = *(const f32x4*)&agg[(size_t)n * HH + f0];
    f32x4 h  = *(const f32x4*)&hbuf[(size_t)n * HH + f0];
    f32x4 rt = *(const f32x4*)&root[f0];
    f32x4 gm = *(const f32x4*)&gamma[f0];
    f32x4 bt = *(const f32x4*)&beta[f0];
    f32x4 mn = *(const f32x4*)&mean[f0];
    f32x4 vr = *(const f32x4*)&var[f0];
    float di = 1.f / deg[n];
    ubf16x4 o;
#pragma unroll
    for (int j = 0; j < 4; ++j) {
        float self = fmaxf(h[j] + rt[j], 0.f) * di;
        float v = fmaxf(a[j] + self, 0.f);
        v = (v - mn[j]) * rsqrtf(vr[j] + 1e-5f) * gm[j] + bt[j];
        o[j] = f2bf(v);
    }
    *(ubf16x4*)&featsbf[(size_t)n * CAT + f0] = o;
    *(ubf16x4*)&hb[(size_t)n * HH + f0] = o;
}

// ---------------- launch ----------------------------------------------------------
extern "C" void kernel_launch(void* const* d_in, const int* in_sizes, int n_in,
                              void* d_out, int out_size, void* d_ws, size_t ws_size,
                              hipStream_t stream)
{
    const float* x         = (const float*)d_in[0];
    const int*   eidx      = (const int*)d_in[1];
    const float* edge_attr = (const float*)d_in[2];
    const float* gcn_lin_w = (const float*)d_in[3];
    const float* gcn_lin_b = (const float*)d_in[4];
    const float* gcn_root  = (const float*)d_in[5];
    const float* gcn_bw1   = (const float*)d_in[6];
    const float* gcn_bb1   = (const float*)d_in[7];
    const float* gcn_bw2   = (const float*)d_in[8];
    const float* gcn_bb2   = (const float*)d_in[9];
    const float* gin_bw1   = (const float*)d_in[10];
    const float* gin_bb1   = (const float*)d_in[11];
    const float* gin_bw2   = (const float*)d_in[12];
    const float* gin_bb2   = (const float*)d_in[13];
    const float* gin_mw1   = (const float*)d_in[14];
    const float* gin_mb1   = (const float*)d_in[15];
    const float* gin_mw2   = (const float*)d_in[16];
    const float* gin_mb2   = (const float*)d_in[17];
    const float* gin_eps   = (const float*)d_in[18];
    const float* bn_gamma  = (const float*)d_in[19];
    const float* bn_beta   = (const float*)d_in[20];
    const float* bn_mean   = (const float*)d_in[21];
    const float* bn_var    = (const float*)d_in[22];
    const float* fc1_w     = (const float*)d_in[23];
    const float* fc1_b     = (const float*)d_in[24];
    const float* fc2_w     = (const float*)d_in[25];
    const float* fc2_b     = (const float*)d_in[26];
    float* out = (float*)d_out;

    const int N = in_sizes[0] / 128;   // 50000
    const int E = in_sizes[1] / 2;     // 800000
    const int* row = eidx;
    const int* col = eidx + E;

    // ws layout (bytes)
    char* ws = (char*)d_ws;
    float* deg        = (float*)(ws);                          // N f32
    float* dinv       = (float*)(ws + (size_t)256 * 1024);     // N f32
    int*   seg_start  = (int*)(ws + (size_t)512 * 1024);       // N+1
    int*   cursor     = (int*)(ws + (size_t)768 * 1024);       // N (also hist cnt)
    int*   bsum       = (int*)(ws + (size_t)1024 * 1024);      // 256
    int*   row_sorted = (int*)(ws + (size_t)1088 * 1024);      // E (3.2MB)
    unsigned short* ea_sorted = (unsigned short*)(ws + (size_t)8 * 1024 * 1024);    // E*16 bf16
    unsigned short* hb        = (unsigned short*)(ws + (size_t)34 * 1024 * 1024);   // N*96 bf16
    float* hbuf   = (float*)(ws + (size_t)44 * 1024 * 1024);   // N*96 f32
    float* agg    = (float*)(ws + (size_t)64 * 1024 * 1024);   // N*96 f32
    unsigned short* featsbf = (unsigned short*)(ws + (size_t)84 * 1024 * 1024);     // N*288 bf16
    unsigned short* z1bf    = (unsigned short*)(ws + (size_t)113 * 1024 * 1024);    // N*96 bf16
    unsigned short* r1bf    = (unsigned short*)(ws + (size_t)123 * 1024 * 1024);    // N*96 bf16

    const int ew_blocks = 1024;                     // 4 blocks/CU x 256 CU
    const int q_grid = (N * (HH / 4) + 255) / 256;
    const int gemm_grid = (N + 63) / 64;
    const int e_grid = (E + 255) / 256;
    const int n_grid = (N + 255) / 256;
    const int nchunks = (N + 255) / 256;

    // ---- degrees + CSR build ----
    init_kernel<<<n_grid, 256, 0, stream>>>(deg, cursor, N);
    count_kernel<<<e_grid, 256, 0, stream>>>(row, col, deg, cursor, E);
    scan1_kernel<<<nchunks, 256, 0, stream>>>(cursor, seg_start, bsum, N);
    scan2_kernel<<<1, 256, 0, stream>>>(bsum, nchunks);
    scan3_kernel<<<(N + 256) / 256, 256, 0, stream>>>(seg_start, bsum, cursor, deg, dinv, N, E);
    scatter_ea_kernel<<<e_grid, 256, 0, stream>>>(row, col, cursor, edge_attr,
                                                  row_sorted, ea_sorted, E);

    // ---- layer 0: GCN ----
    node_gemm<128, 96, 0, 3><<<gemm_grid, 256, 0, stream>>>(
        x, 128, nullptr, nullptr, 0, gcn_lin_w, gcn_lin_b,
        hbuf, HH, hb, nullptr, nullptr, nullptr, nullptr, N);
    edge_kernel<true><<<ew_blocks, 256, 0, stream>>>(
        ea_sorted, row_sorted, seg_start,
        gcn_bw1, gcn_bb1, gcn_bw2, gcn_bb2, hb, dinv, agg, N);
    gcn_epilogue_kernel<<<q_grid, 256, 0, stream>>>(
        agg, hbuf, gcn_root, deg, bn_gamma, bn_beta, bn_mean, bn_var, featsbf, hb, N);

    // ---- layers 1..2: GIN ----
    for (int i = 0; i < 2; ++i) {
        edge_kernel<false><<<ew_blocks, 256, 0, stream>>>(
            ea_sorted, row_sorted, seg_start,
            gin_bw1 + (size_t)i * EDGEF * HH, gin_bb1 + i * HH,
            gin_bw2 + (size_t)i * HH * HH, gin_bb2 + i * HH,
            hb, dinv, agg, N);
        // z1 = relu((1+eps)*h + agg) @ mw1 + mb1  -> bf16 (h read dense from hb)
        node_gemm<96, 96, 2, 1><<<gemm_grid, 256, 0, stream>>>(
            hb, HH, agg, gin_eps, i,
            gin_mw1 + (size_t)i * HH * HH, gin_mb1 + i * HH,
            z1bf, HH, nullptr, nullptr, nullptr, nullptr, nullptr, N);
        // feats[i+1] = BN(relu(z1 @ mw2 + mb2)) -> strided featsbf + dense hb
        node_gemm<96, 96, 1, 2><<<gemm_grid, 256, 0, stream>>>(
            z1bf, HH, nullptr, nullptr, 0,
            gin_mw2 + (size_t)i * HH * HH, gin_mb2 + i * HH,
            featsbf + (i + 1) * HH, CAT, hb,
            bn_gamma + (i + 1) * HH, bn_beta + (i + 1) * HH,
            bn_mean + (i + 1) * HH, bn_var + (i + 1) * HH, N);
    }

    // ---- head ----
    node_gemm<288, 96, 1, 1><<<gemm_grid, 256, 0, stream>>>(
        featsbf, CAT, nullptr, nullptr, 0, fc1_w, fc1_b,
        r1bf, HH, nullptr, nullptr, nullptr, nullptr, nullptr, N);
    node_gemm<96, 64, 1, 0><<<gemm_grid, 256, 0, stream>>>(
        r1bf, HH, nullptr, nullptr, 0, fc2_w, fc2_b,
        out, 64, nullptr, nullptr, nullptr, nullptr, nullptr, N);
}